// Round 9
// baseline (55.058 us; speedup 1.0000x reference)
//
#include <hip/hip_runtime.h>
#include <stdint.h>

#define NS 9

typedef _Float16 f16x8 __attribute__((ext_vector_type(8)));
typedef float    f32x4 __attribute__((ext_vector_type(4)));

#define SBAR __builtin_amdgcn_sched_barrier(0)
#define WAIT_VM(N) do { SBAR; asm volatile("s_waitcnt vmcnt(" #N ")" ::: "memory"); SBAR; } while (0)
#define WAIT_LGKM0 do { SBAR; asm volatile("s_waitcnt lgkmcnt(0)" ::: "memory"); SBAR; } while (0)

__device__ __forceinline__ unsigned int pk(float a, float b) {
    return __builtin_bit_cast(unsigned int, __builtin_amdgcn_cvt_pkrtz(a, b));
}

// out[b,h,A,C,j] = sum_d q[b,h,A,C,d]*relw[63+j-C,d] + q[b,h,C,A,d]*relh[63+j-C,d]
// v9: 16x16 (A x C) output tiles -> ALL global q loads are sequential-coalesced
// (v2-v8 shared a ~32-scattered-lines-per-instr load pattern; that was the
// invariant floor). Block = (bh, ta, tc): stages S1=q[Ta,Tc,:], S2=q[Tc,Ta,:]
// (each 16 rows x 4KiB contiguous) + 32 rows of each rel table, all coalesced,
// 36 loads deep before first wait; converts to f16 LDS with per-tensor XOR
// swizzles sized so every ds b128 op is bank-quad-uniform (inherent 8-phase
// floor): S1 swizzled by row (read along dim0), S2 by col (read along dim1),
// RL by rel row. Wave w computes c_local = 4w+it, it=0..3: 4 MFMA each
// (2 terms x 2 K-halves), frags all ds_read_b128, B pre-converted (no loop cvt).
// MFMA layouts inherited from v7/v8 (passed): A row=lane&15, d=ks*32+
// (lane>>4)*8+i; B col=lane&15 -> rel row 63-c+j (cols j>=9 junk, unstored);
// C/D col=lane&15, row=(lane>>4)*4+reg.

__global__ __launch_bounds__(256, 2) void relpos_kernel(
    const float* __restrict__ q,
    const float* __restrict__ relh,
    const float* __restrict__ relw,
    float* __restrict__ out)
{
    __shared__ uint4 S1[16][16][8];   // 32 KiB f16: S1[a][cc][chunk^(a&7)]
    __shared__ uint4 S2[16][16][8];   // 32 KiB f16: S2[r][cc][chunk^(cc&7)]
    __shared__ uint4 RL[2][32][8];    // 16 KiB f16: RL[t][row][chunk^(row&7)]

    const int bh   = blockIdx.x & 127;      // b*8+h; same-bh -> same XCD
    const int tile = blockIdx.x >> 7;       // 0..15
    const int Ta0  = (tile >> 2) << 4;
    const int Tc0  = (tile & 3) << 4;

    const int t    = threadIdx.x;
    const int lane = t & 63;
    const int wvu  = __builtin_amdgcn_readfirstlane(t >> 6);
    const int jl   = lane & 15;
    const int k4p  = lane >> 4;

    const float* __restrict__ qs = q + ((size_t)bh << 18);
    const int rbase = 48 - Tc0;             // rel window start (rows rbase..+31)

    const int hrow = t >> 7;                // 0/1: which of 2 rows per pass
    const int u    = t & 127;               // 32-B unit within 4-KiB row span
    const int cc   = u >> 3;
    const int k4   = u & 7;

    // ---- issue all 36 loads (coalesced), then counted waits ----
    float4 sA[16], sB[16], sR[4];
#pragma unroll
    for (int p = 0; p < 8; ++p) {           // S1: 16 loads
        const int a = 2 * p + hrow;
        const float* g1 = qs + (size_t)(Ta0 + a) * 4096 + (size_t)(Tc0 + cc) * 64 + k4 * 8;
        sA[2 * p]     = *(const float4*)g1;
        sA[2 * p + 1] = *(const float4*)(g1 + 4);
    }
    SBAR;
#pragma unroll
    for (int p = 0; p < 8; ++p) {           // S2: 16 loads
        const int a = 2 * p + hrow;
        const float* g2 = qs + (size_t)(Tc0 + a) * 4096 + (size_t)(Ta0 + cc) * 64 + k4 * 8;
        sB[2 * p]     = *(const float4*)g2;
        sB[2 * p + 1] = *(const float4*)(g2 + 4);
    }
    SBAR;
    // rel: 512 chunks (2 tbl x 32 rows x 8); thread t covers chunks 2t, 2t+1
    const int ch0 = t << 1;
    const int tb0 = ch0 >> 8, row0 = (ch0 >> 3) & 31, kk0 = ch0 & 7;
    const int ch1 = ch0 + 1;
    const int tb1 = ch1 >> 8, row1 = (ch1 >> 3) & 31, kk1 = ch1 & 7;
    {
        int gr0 = rbase + row0; gr0 = gr0 > 71 ? 71 : gr0;
        int gr1 = rbase + row1; gr1 = gr1 > 71 ? 71 : gr1;
        const float* rp0 = (tb0 ? relw : relh) + (size_t)gr0 * 64 + kk0 * 8;
        const float* rp1 = (tb1 ? relw : relh) + (size_t)gr1 * 64 + kk1 * 8;
        sR[0] = *(const float4*)rp0; sR[1] = *(const float4*)(rp0 + 4);
        sR[2] = *(const float4*)rp1; sR[3] = *(const float4*)(rp1 + 4);
    }
    SBAR;

    WAIT_VM(20);                            // S1 landed (oldest 16 of 36)
#pragma unroll
    for (int p = 0; p < 8; ++p) {
        const int a = 2 * p + hrow;
        uint4 w;
        w.x = pk(sA[2 * p].x,     sA[2 * p].y);
        w.y = pk(sA[2 * p].z,     sA[2 * p].w);
        w.z = pk(sA[2 * p + 1].x, sA[2 * p + 1].y);
        w.w = pk(sA[2 * p + 1].z, sA[2 * p + 1].w);
        S1[a][cc][k4 ^ (a & 7)] = w;        // swizzle by row a
    }
    WAIT_VM(4);                             // S2 landed
#pragma unroll
    for (int p = 0; p < 8; ++p) {
        const int a = 2 * p + hrow;
        uint4 w;
        w.x = pk(sB[2 * p].x,     sB[2 * p].y);
        w.y = pk(sB[2 * p].z,     sB[2 * p].w);
        w.z = pk(sB[2 * p + 1].x, sB[2 * p + 1].y);
        w.w = pk(sB[2 * p + 1].z, sB[2 * p + 1].w);
        S2[a][cc][k4 ^ (cc & 7)] = w;       // swizzle by col cc
    }
    WAIT_VM(0);                             // rel landed
    {
        uint4 w0, w1;
        w0.x = pk(sR[0].x, sR[0].y); w0.y = pk(sR[0].z, sR[0].w);
        w0.z = pk(sR[1].x, sR[1].y); w0.w = pk(sR[1].z, sR[1].w);
        w1.x = pk(sR[2].x, sR[2].y); w1.y = pk(sR[2].z, sR[2].w);
        w1.z = pk(sR[3].x, sR[3].y); w1.w = pk(sR[3].z, sR[3].w);
        RL[tb0][row0][kk0 ^ (row0 & 7)] = w0;
        RL[tb1][row1][kk1 ^ (row1 & 7)] = w1;
    }
    WAIT_LGKM0;
    __builtin_amdgcn_s_barrier();           // publish LDS (writes drained above)

    // ---- compute: issue all 32 frag reads, one wait, 16 MFMA ----
    uint4 ra[16], rb[16];
#pragma unroll
    for (int it = 0; it < 4; ++it) {
        const int cl = (wvu << 2) | it;     // wave-uniform c_local
        ra[it * 4 + 0] = S1[jl][cl][(k4p)     ^ (jl & 7)];
        ra[it * 4 + 1] = S1[jl][cl][(4 + k4p) ^ (jl & 7)];
        ra[it * 4 + 2] = S2[cl][jl][(k4p)     ^ (jl & 7)];
        ra[it * 4 + 3] = S2[cl][jl][(4 + k4p) ^ (jl & 7)];
        int rl = 15 - cl + jl;
        if (rl > 23) rl = 16 + jl;          // padding cols -> spare rows (junk)
        rb[it * 4 + 0] = RL[1][rl][(k4p)     ^ (rl & 7)];   // relw, k-half 0
        rb[it * 4 + 1] = RL[1][rl][(4 + k4p) ^ (rl & 7)];   // relw, k-half 1
        rb[it * 4 + 2] = RL[0][rl][(k4p)     ^ (rl & 7)];   // relh, k-half 0
        rb[it * 4 + 3] = RL[0][rl][(4 + k4p) ^ (rl & 7)];   // relh, k-half 1
    }
    WAIT_LGKM0;

    f32x4 acc[4];
#pragma unroll
    for (int it = 0; it < 4; ++it) acc[it] = (f32x4){0.f, 0.f, 0.f, 0.f};
#pragma unroll
    for (int r = 0; r < 4; ++r)             // rotate accs: dep distance 4
#pragma unroll
        for (int it = 0; it < 4; ++it)
            acc[it] = __builtin_amdgcn_mfma_f32_16x16x32_f16(
                __builtin_bit_cast(f16x8, ra[it * 4 + r]),
                __builtin_bit_cast(f16x8, rb[it * 4 + r]),
                acc[it], 0, 0, 0);

    // ---- store: col j=lane&15 (<9), row a=(lane>>4)*4+reg ----
    if (jl < NS) {
        const int ar = k4p << 2;
        const size_t ob = (size_t)bh << 6;
#pragma unroll
        for (int it = 0; it < 4; ++it) {
            const int c = Tc0 + ((wvu << 2) | it);
#pragma unroll
            for (int r = 0; r < 4; ++r)
                out[((ob + (Ta0 + ar + r)) * 64 + c) * NS + jl] = acc[it][r];
        }
    }
}

extern "C" void kernel_launch(void* const* d_in, const int* in_sizes, int n_in,
                              void* d_out, int out_size, void* d_ws, size_t ws_size,
                              hipStream_t stream) {
    const float* q    = (const float*)d_in[0];
    const float* relh = (const float*)d_in[3];
    const float* relw = (const float*)d_in[4];
    float* out = (float*)d_out;

    // grid: 16 (ta,tc) tiles x 128 (b,h); same-bh blocks 128 apart -> same XCD
    relpos_kernel<<<dim3(2048), dim3(256), 0, stream>>>(q, relh, relw, out);
}

// Round 10
// 37.167 us; speedup vs baseline: 1.4814x; 1.4814x over previous
//
#include <hip/hip_runtime.h>
#include <stdint.h>

#define NS 9

typedef _Float16 f16x8 __attribute__((ext_vector_type(8)));
typedef float    f32x4 __attribute__((ext_vector_type(4)));

#define SBAR __builtin_amdgcn_sched_barrier(0)
#define WAIT_VM(N) do { SBAR; asm volatile("s_waitcnt vmcnt(" #N ")" ::: "memory"); SBAR; } while (0)
#define WAIT_LGKM0 do { SBAR; asm volatile("s_waitcnt lgkmcnt(0)" ::: "memory"); SBAR; } while (0)

__device__ __forceinline__ unsigned int pk(float a, float b) {
    return __builtin_bit_cast(unsigned int, __builtin_amdgcn_cvt_pkrtz(a, b));
}

// out[b,h,A,C,j] = sum_d q[b,h,A,C,d]*relw[63+j-C,d] + q[b,h,C,A,d]*relh[63+j-C,d]
// v10: symmetric-pair merge. Block (bh, ta<=tc) stages S1=q[Ta,Tc,:] and
// S2=q[Tc,Ta,:] ONCE and computes BOTH output tiles (ta,tc) and (tc,ta)
// (role swap: out(ta,tc)=S1*relw[win c]+S2*relh[win c]; out(tc,ta)=
// S2*relw[win a]+S1*relh[win a]). Grid 1280 = 128 bh x 10 tile-pairs ->
// q staging instructions per output HALVED vs v9. All staging coalesced;
// symmetric XOR swizzle key (a^cc)&7 so S tiles are conflict-spread under
// BOTH row-wise (pass 1) and col-wise (pass 2) fragment reads. Rel: 2 windows
// (rbase 48-Tc0 / 48-Ta0, 24 rows valid, 32 padded) x 2 tables, coalesced,
// 3 chunks/thread. Counted-vmcnt drain, one barrier, 16 MFMA per pass.
// MFMA layouts HW-verified by v7-v9: A row=lane&15, d=ks*32+(lane>>4)*8+i;
// B col=lane&15 -> rel row (15-cl)+jl in-window; C/D col=lane&15,
// row=(lane>>4)*4+reg. Junk cols j>=9 may read junk rel rows 24..31 (in
// bounds, never stored).

__global__ __launch_bounds__(256, 2) void relpos_kernel(
    const float* __restrict__ q,
    const float* __restrict__ relh,
    const float* __restrict__ relw,
    float* __restrict__ out)
{
    __shared__ uint4 S1[16][16][8];      // 32 KiB f16: q[Ta0+a][Tc0+cc]
    __shared__ uint4 S2[16][16][8];      // 32 KiB f16: q[Tc0+a][Ta0+cc]
    __shared__ uint4 RL[2][2][32][8];    // 16 KiB f16: [win][tbl][row][chunk]

    const int bh  = blockIdx.x & 127;    // b*8+h; same-bh stride 128 -> same XCD
    const int wid = blockIdx.x >> 7;     // 0..9 upper-triangle tile pair
    const int ta  = wid < 4 ? 0 : wid < 7 ? 1 : wid < 9 ? 2 : 3;
    const int tc  = wid < 4 ? wid : wid < 7 ? wid - 3 : wid < 9 ? wid - 5 : 3;
    const int Ta0 = ta << 4, Tc0 = tc << 4;

    const int t    = threadIdx.x;
    const int lane = t & 63;
    const int wvu  = __builtin_amdgcn_readfirstlane(t >> 6);
    const int jl   = lane & 15;
    const int k4p  = lane >> 4;

    const float* __restrict__ qs = q + ((size_t)bh << 18);

    const int hrow = t >> 7;             // 0/1
    const int u    = t & 127;
    const int cc   = u >> 3;
    const int k4   = u & 7;

    // ---- issue all 38 loads (coalesced), then counted drains ----
    float4 sA[16], sB[16], sR[6];
#pragma unroll
    for (int p = 0; p < 8; ++p) {        // S1: q[Ta0+a][Tc0+cc]
        const int a = 2 * p + hrow;
        const float* g1 = qs + (size_t)(Ta0 + a) * 4096 + (size_t)(Tc0 + cc) * 64 + k4 * 8;
        sA[2 * p]     = *(const float4*)g1;
        sA[2 * p + 1] = *(const float4*)(g1 + 4);
    }
    SBAR;
#pragma unroll
    for (int p = 0; p < 8; ++p) {        // S2: q[Tc0+a][Ta0+cc]
        const int a = 2 * p + hrow;
        const float* g2 = qs + (size_t)(Tc0 + a) * 4096 + (size_t)(Ta0 + cc) * 64 + k4 * 8;
        sB[2 * p]     = *(const float4*)g2;
        sB[2 * p + 1] = *(const float4*)(g2 + 4);
    }
    SBAR;
    // rel: 768 chunks = [win 2][tbl 2][row 24][k 8]; thread t: chunks t+256m
#pragma unroll
    for (int m = 0; m < 3; ++m) {
        int ch  = t + (m << 8);
        int win = ch >= 384;  int r = ch - (win ? 384 : 0);
        int tbl = r >= 192;   r -= (tbl ? 192 : 0);
        const int row = r >> 3, kk = r & 7;
        const int rb0 = win ? (48 - Ta0) : (48 - Tc0);   // rows rb0..rb0+23 <= 71
        const float* rp = (tbl ? relw : relh) + (size_t)(rb0 + row) * 64 + kk * 8;
        sR[2 * m]     = *(const float4*)rp;
        sR[2 * m + 1] = *(const float4*)(rp + 4);
    }
    SBAR;

    WAIT_VM(22);                          // S1 landed
#pragma unroll
    for (int p = 0; p < 8; ++p) {
        const int a = 2 * p + hrow;
        uint4 w;
        w.x = pk(sA[2 * p].x,     sA[2 * p].y);
        w.y = pk(sA[2 * p].z,     sA[2 * p].w);
        w.z = pk(sA[2 * p + 1].x, sA[2 * p + 1].y);
        w.w = pk(sA[2 * p + 1].z, sA[2 * p + 1].w);
        S1[a][cc][k4 ^ ((a ^ cc) & 7)] = w;
    }
    WAIT_VM(6);                           // S2 landed
#pragma unroll
    for (int p = 0; p < 8; ++p) {
        const int a = 2 * p + hrow;
        uint4 w;
        w.x = pk(sB[2 * p].x,     sB[2 * p].y);
        w.y = pk(sB[2 * p].z,     sB[2 * p].w);
        w.z = pk(sB[2 * p + 1].x, sB[2 * p + 1].y);
        w.w = pk(sB[2 * p + 1].z, sB[2 * p + 1].w);
        S2[a][cc][k4 ^ ((a ^ cc) & 7)] = w;
    }
    WAIT_VM(0);                           // rel landed
#pragma unroll
    for (int m = 0; m < 3; ++m) {
        int ch  = t + (m << 8);
        int win = ch >= 384;  int r = ch - (win ? 384 : 0);
        int tbl = r >= 192;   r -= (tbl ? 192 : 0);
        const int row = r >> 3, kk = r & 7;
        uint4 w;
        w.x = pk(sR[2 * m].x,     sR[2 * m].y);
        w.y = pk(sR[2 * m].z,     sR[2 * m].w);
        w.z = pk(sR[2 * m + 1].x, sR[2 * m + 1].y);
        w.w = pk(sR[2 * m + 1].z, sR[2 * m + 1].w);
        RL[win][tbl][row][kk ^ (row & 7)] = w;
    }
    WAIT_LGKM0;
    __builtin_amdgcn_s_barrier();         // publish LDS

    // ---- one pass = one 16x16 output tile (16 MFMA/wave) ----
    auto pass = [&](const uint4 (*P)[16][8], const uint4 (*Q)[16][8], int w,
                    int Arow0, int Ccol0) {
        uint4 ra[16], rb[16];
#pragma unroll
        for (int it = 0; it < 4; ++it) {
            const int cl = (wvu << 2) | it;
            const int sx = (jl ^ cl) & 7;
            ra[it * 4 + 0] = P[jl][cl][(k4p)     ^ sx];   // A (relw term), k0
            ra[it * 4 + 1] = P[jl][cl][(4 + k4p) ^ sx];   // k1
            ra[it * 4 + 2] = Q[cl][jl][(k4p)     ^ sx];   // A (relh term), k0
            ra[it * 4 + 3] = Q[cl][jl][(4 + k4p) ^ sx];   // k1
            const int rl = (15 - cl) + jl;                // 0..30; junk if jl>=9
            rb[it * 4 + 0] = RL[w][1][rl][(k4p)     ^ (rl & 7)];  // relw k0
            rb[it * 4 + 1] = RL[w][1][rl][(4 + k4p) ^ (rl & 7)];  // relw k1
            rb[it * 4 + 2] = RL[w][0][rl][(k4p)     ^ (rl & 7)];  // relh k0
            rb[it * 4 + 3] = RL[w][0][rl][(4 + k4p) ^ (rl & 7)];  // relh k1
        }
        WAIT_LGKM0;

        f32x4 acc[4];
#pragma unroll
        for (int it = 0; it < 4; ++it) acc[it] = (f32x4){0.f, 0.f, 0.f, 0.f};
#pragma unroll
        for (int r = 0; r < 4; ++r)
#pragma unroll
            for (int it = 0; it < 4; ++it)
                acc[it] = __builtin_amdgcn_mfma_f32_16x16x32_f16(
                    __builtin_bit_cast(f16x8, ra[it * 4 + r]),
                    __builtin_bit_cast(f16x8, rb[it * 4 + r]),
                    acc[it], 0, 0, 0);

        if (jl < NS) {
            const int ar = k4p << 2;
            const size_t ob = (size_t)bh << 6;
#pragma unroll
            for (int it = 0; it < 4; ++it) {
                const int cl = (wvu << 2) | it;
#pragma unroll
                for (int r = 0; r < 4; ++r)
                    out[((ob + (Arow0 + ar + r)) * 64 + (Ccol0 + cl)) * NS + jl] = acc[it][r];
            }
        }
    };

    pass(S1, S2, 0, Ta0, Tc0);            // out tile (ta, tc)
    if (ta != tc)
        pass(S2, S1, 1, Tc0, Ta0);        // twin tile (tc, ta), same q staging
}

extern "C" void kernel_launch(void* const* d_in, const int* in_sizes, int n_in,
                              void* d_out, int out_size, void* d_ws, size_t ws_size,
                              hipStream_t stream) {
    const float* q    = (const float*)d_in[0];
    const float* relh = (const float*)d_in[3];
    const float* relw = (const float*)d_in[4];
    float* out = (float*)d_out;

    // grid: 10 upper-triangle tile pairs x 128 (b,h)
    relpos_kernel<<<dim3(1280), dim3(256), 0, stream>>>(q, relh, relw, out);
}